// Round 8
// baseline (129.221 us; speedup 1.0000x reference)
//
#include <hip/hip_runtime.h>
#include <math.h>

#define DIM 128
#define NUM_NEG 20
#define BATCH 16384
#define INV_T (1.0f / 0.07f)
#define NROWS 21
#define NPAD 24              // padded row-count for 16B-aligned partials
#define NUM_NODES 100000
#define NSLICE 8
#define DSL (DIM / NSLICE)   // 16 dims per slice -> 32 B fp16 per (slice,node)

typedef _Float16 half8 __attribute__((ext_vector_type(8)));

// ---- convert: emb[n][128] fp32 -> slice-major fp16 tabs[s][n][16] ----
// Each slice region is NUM_NODES*32 B = 3.2 MB -> fits one XCD's 4 MB L2.
__global__ __launch_bounds__(256) void convert_sliced(
    const float* __restrict__ in, half8* __restrict__ tabs)
{
    const int n = blockIdx.x * 256 + threadIdx.x;
    const int s = blockIdx.y;
    if (n >= NUM_NODES) return;
    const float4* p =
        reinterpret_cast<const float4*>(in + (size_t)n * DIM + s * DSL);
    const float4 a = p[0], b = p[1], c = p[2], d = p[3];
    half8 h0, h1;
    h0[0]=(_Float16)a.x; h0[1]=(_Float16)a.y; h0[2]=(_Float16)a.z; h0[3]=(_Float16)a.w;
    h0[4]=(_Float16)b.x; h0[5]=(_Float16)b.y; h0[6]=(_Float16)b.z; h0[7]=(_Float16)b.w;
    h1[0]=(_Float16)c.x; h1[1]=(_Float16)c.y; h1[2]=(_Float16)c.z; h1[3]=(_Float16)c.w;
    h1[4]=(_Float16)d.x; h1[5]=(_Float16)d.y; h1[6]=(_Float16)d.z; h1[7]=(_Float16)d.w;
    half8* o = tabs + ((size_t)s * NUM_NODES + n) * 2;
    o[0] = h0;
    o[1] = h1;
}

// ---- sliced gather: blockIdx.x = slice (x-minor => linear%8 = slice =>
// one slice per XCD under round-robin dispatch; heuristic only, correctness
// does not depend on it). Each lane handles ONE (batch-elem, row) pair for
// this slice: 2x16B row load + 2x16B target load (broadcast across the
// elem's 21 lanes), 16-dim partial dot fully in-lane, NT-store 4B partial.
__global__ __launch_bounds__(256) void gather_sliced(
    const half8* __restrict__ tabs,
    const int* __restrict__ targets,
    const int* __restrict__ contexts,
    const int* __restrict__ negatives,
    float* __restrict__ part)        // [NSLICE][BATCH][NPAD]
{
    const int s    = blockIdx.x;
    const int lane = threadIdx.x & 63;
    const int wib  = threadIdx.x >> 6;
    if (lane >= 63) return;
    const int e = lane / 21;         // 0..2 (3 elems per wave)
    const int r = lane - e * 21;     // 0..20
    const int b = blockIdx.y * 12 + wib * 3 + e;
    if (b >= BATCH) return;

    const int node = (r == 0) ? contexts[b] : negatives[b * NUM_NEG + (r - 1)];
    const int t    = targets[b];

    const half8* tp = tabs + ((size_t)s * NUM_NODES + t) * 2;
    const half8* vp = tabs + ((size_t)s * NUM_NODES + node) * 2;
    const half8 t0 = tp[0], t1 = tp[1];
    const half8 v0 = vp[0], v1 = vp[1];

    float p = 0.0f;
    #pragma unroll
    for (int j = 0; j < 8; ++j) p = fmaf((float)t0[j], (float)v0[j], p);
    #pragma unroll
    for (int j = 0; j < 8; ++j) p = fmaf((float)t1[j], (float)v1[j], p);

    __builtin_nontemporal_store(
        p, &part[((size_t)s * BATCH + b) * NPAD + r]);
}

// ---- combine: sum 8 slice-partials per row, logsumexp, mean-loss ----
__global__ __launch_bounds__(256) void combine_loss(
    const float* __restrict__ part, float* __restrict__ out)
{
    __shared__ float ws[4];
    const int b = blockIdx.x * 256 + threadIdx.x;

    float sc[NROWS];
    #pragma unroll
    for (int r = 0; r < NROWS; ++r) sc[r] = 0.0f;
    #pragma unroll
    for (int s = 0; s < NSLICE; ++s) {
        const float4* p4 = reinterpret_cast<const float4*>(
            part + ((size_t)s * BATCH + b) * NPAD);
        #pragma unroll
        for (int q = 0; q < 5; ++q) {       // 5 x float4 = rows 0..19
            const float4 v = p4[q];
            sc[q * 4 + 0] += v.x;
            sc[q * 4 + 1] += v.y;
            sc[q * 4 + 2] += v.z;
            sc[q * 4 + 3] += v.w;
        }
        sc[20] += part[((size_t)s * BATCH + b) * NPAD + 20];
    }

    float m = sc[0] * INV_T;
    #pragma unroll
    for (int r = 0; r < NROWS; ++r) { sc[r] *= INV_T; m = fmaxf(m, sc[r]); }
    float sum = 0.0f;
    #pragma unroll
    for (int r = 0; r < NROWS; ++r) sum += expf(sc[r] - m);
    float loss = (m + logf(sum) - sc[0]) * (1.0f / BATCH);

    #pragma unroll
    for (int off = 32; off; off >>= 1) loss += __shfl_xor(loss, off);
    const int wave = threadIdx.x >> 6;
    if ((threadIdx.x & 63) == 0) ws[wave] = loss;
    __syncthreads();
    if (threadIdx.x == 0)
        atomicAdd(out, ws[0] + ws[1] + ws[2] + ws[3]);   // 64 blocks total
}

// ---- fp32 fallback with atomic ending (only if d_ws is tiny) ----
__global__ __launch_bounds__(256) void infonce_f32_atomic(
    const float* __restrict__ emb,
    const int* __restrict__ targets,
    const int* __restrict__ contexts,
    const int* __restrict__ negatives,
    float* __restrict__ out)
{
    __shared__ float block_part[4];
    const int lane = threadIdx.x & 63;
    const int wib  = threadIdx.x >> 6;
    const int b    = blockIdx.x * 4 + wib;
    const int sub  = lane & 15;
    const int grp  = lane >> 4;

    const int* __restrict__ negb = negatives + b * NUM_NEG;
    int node[6];
    #pragma unroll
    for (int it = 0; it < 6; ++it) {
        const int r = it * 4 + grp;
        const int k = (r == 0) ? 0 : ((r <= NUM_NEG) ? (r - 1) : (NUM_NEG - 1));
        node[it] = (r == 0) ? contexts[b] : negb[k];
    }
    const int t_idx = targets[b];

    const float4* tp =
        reinterpret_cast<const float4*>(emb + (size_t)t_idx * DIM + sub * 8);
    const float4 t0 = tp[0];
    const float4 t1 = tp[1];

    float score[6];
    #pragma unroll
    for (int it = 0; it < 6; ++it) {
        const float4* vp = reinterpret_cast<const float4*>(
            emb + (size_t)node[it] * DIM + sub * 8);
        const float4 v0 = vp[0];
        const float4 v1 = vp[1];
        float p = t0.x * v0.x + t0.y * v0.y + t0.z * v0.z + t0.w * v0.w
                + t1.x * v1.x + t1.y * v1.y + t1.z * v1.z + t1.w * v1.w;
        p += __shfl_xor(p, 1);
        p += __shfl_xor(p, 2);
        p += __shfl_xor(p, 4);
        p += __shfl_xor(p, 8);
        const int r = it * 4 + grp;
        score[it] = (r < NROWS) ? p * INV_T : -INFINITY;
    }

    float m = score[0];
    #pragma unroll
    for (int i = 1; i < 6; ++i) m = fmaxf(m, score[i]);
    float s = 0.0f;
    #pragma unroll
    for (int i = 0; i < 6; ++i) s += expf(score[i] - m);

    #pragma unroll
    for (int mask = 16; mask <= 32; mask <<= 1) {
        const float mo = __shfl_xor(m, mask);
        const float so = __shfl_xor(s, mask);
        const float mn = fmaxf(m, mo);
        s = s * expf(m - mn) + so * expf(mo - mn);
        m = mn;
    }

    const float pos = __shfl(score[0], 0);
    const float loss = (m + logf(s) - pos) * (1.0f / BATCH);

    if (lane == 0) block_part[wib] = loss;
    __syncthreads();
    if (threadIdx.x == 0) {
        atomicAdd(out, block_part[0] + block_part[1] +
                       block_part[2] + block_part[3]);
    }
}

extern "C" void kernel_launch(void* const* d_in, const int* in_sizes, int n_in,
                              void* d_out, int out_size, void* d_ws, size_t ws_size,
                              hipStream_t stream) {
    const float* emb       = (const float*)d_in[0];
    const int*   targets   = (const int*)d_in[1];
    const int*   contexts  = (const int*)d_in[2];
    const int*   negatives = (const int*)d_in[3];
    float* out = (float*)d_out;

    const size_t tab_bytes  = (size_t)NSLICE * NUM_NODES * DSL * sizeof(_Float16); // 25.6 MB
    const size_t part_bytes = (size_t)NSLICE * BATCH * NPAD * sizeof(float);       // 12.6 MB

    hipMemsetAsync(out, 0, sizeof(float), stream);

    if (ws_size >= tab_bytes + part_bytes) {
        half8* tabs = (half8*)d_ws;
        float* part = (float*)((char*)d_ws + tab_bytes);   // 16B-aligned

        convert_sliced<<<dim3((NUM_NODES + 255) / 256, NSLICE),
                         dim3(256), 0, stream>>>(emb, tabs);
        gather_sliced<<<dim3(NSLICE, (BATCH + 11) / 12),
                        dim3(256), 0, stream>>>(
            tabs, targets, contexts, negatives, part);
        combine_loss<<<dim3(BATCH / 256), dim3(256), 0, stream>>>(part, out);
    } else {
        infonce_f32_atomic<<<dim3(BATCH / 4), dim3(256), 0, stream>>>(
            emb, targets, contexts, negatives, out);
    }
}

// Round 10
// 105.418 us; speedup vs baseline: 1.2258x; 1.2258x over previous
//
#include <hip/hip_runtime.h>
#include <math.h>

#define DIM 128
#define NUM_NEG 20
#define BATCH 16384
#define INV_T (1.0f / 0.07f)
#define NROWS 21
#define NUM_NODES 100000
#define NBLOCK (BATCH / 4)   // 4096 blocks, 4 waves each

typedef _Float16 half8 __attribute__((ext_vector_type(8)));

// ---- fp32 -> fp16 table conversion (streams 51.2 MB -> 25.6 MB in d_ws) ----
__global__ __launch_bounds__(256) void convert_f16(
    const float* __restrict__ in, half8* __restrict__ out, int nchunk)
{
    for (int i = blockIdx.x * blockDim.x + threadIdx.x; i < nchunk;
         i += gridDim.x * blockDim.x) {
        const float4* p = reinterpret_cast<const float4*>(in) + (size_t)i * 2;
        const float4 a = p[0], b = p[1];
        half8 h;
        h[0] = (_Float16)a.x; h[1] = (_Float16)a.y;
        h[2] = (_Float16)a.z; h[3] = (_Float16)a.w;
        h[4] = (_Float16)b.x; h[5] = (_Float16)b.y;
        h[6] = (_Float16)b.z; h[7] = (_Float16)b.w;
        out[i] = h;
    }
}

// ---- fp16 gather kernel: one wave per batch element, 4 groups x 16 lanes.
// 256 B fp16 rows = 4 fully-used 64B lines per row. Block result goes to a
// unique d_ws slot (no same-address atomics -- those cost ~34 cyc each
// serialized and dominated R1-R5). ----
__global__ __launch_bounds__(256) void infonce_f16(
    const half8* __restrict__ tab,   // [NUM_NODES][16] chunks of 8 halves
    const int* __restrict__ targets,
    const int* __restrict__ contexts,
    const int* __restrict__ negatives,
    float* __restrict__ part)        // [NBLOCK] partials
{
    __shared__ float block_part[4];
    const int lane = threadIdx.x & 63;
    const int wib  = threadIdx.x >> 6;
    const int b    = blockIdx.x * 4 + wib;
    const int sub  = lane & 15;          // 8-half chunk within the row
    const int grp  = lane >> 4;          // row-group 0..3

    // phase 1: all index loads
    const int* __restrict__ negb = negatives + b * NUM_NEG;
    int node[6];
    #pragma unroll
    for (int it = 0; it < 6; ++it) {
        const int r = it * 4 + grp;      // 0..23 (21..23 invalid -> alias row 20)
        const int k = (r == 0) ? 0 : ((r <= NUM_NEG) ? (r - 1) : (NUM_NEG - 1));
        node[it] = (r == 0) ? contexts[b] : negb[k];
    }
    const int t_idx = targets[b];

    // phase 2: all row gathers back-to-back (max MLP)
    const half8 th = tab[(size_t)t_idx * 16 + sub];
    half8 vh[6];
    #pragma unroll
    for (int it = 0; it < 6; ++it)
        vh[it] = tab[(size_t)node[it] * 16 + sub];

    float tf[8];
    #pragma unroll
    for (int j = 0; j < 8; ++j) tf[j] = (float)th[j];

    // phase 3: dot + 16-lane reduce per slot
    float score[6];
    #pragma unroll
    for (int it = 0; it < 6; ++it) {
        float p = 0.0f;
        #pragma unroll
        for (int j = 0; j < 8; ++j) p = fmaf(tf[j], (float)vh[it][j], p);
        p += __shfl_xor(p, 1);
        p += __shfl_xor(p, 2);
        p += __shfl_xor(p, 4);
        p += __shfl_xor(p, 8);
        const int r = it * 4 + grp;
        score[it] = (r < NROWS) ? p * INV_T : -INFINITY;
    }

    // phase 4: logsumexp (local 6, then merge across 4 groups)
    float m = score[0];
    #pragma unroll
    for (int i = 1; i < 6; ++i) m = fmaxf(m, score[i]);
    float s = 0.0f;
    #pragma unroll
    for (int i = 0; i < 6; ++i) s += expf(score[i] - m);

    #pragma unroll
    for (int mask = 16; mask <= 32; mask <<= 1) {
        const float mo = __shfl_xor(m, mask);
        const float so = __shfl_xor(s, mask);
        const float mn = fmaxf(m, mo);
        s = s * expf(m - mn) + so * expf(mo - mn);
        m = mn;
    }

    const float pos = __shfl(score[0], 0);
    const float loss = (m + logf(s) - pos) * (1.0f / BATCH);

    if (lane == 0) block_part[wib] = loss;
    __syncthreads();
    if (threadIdx.x == 0) {
        part[blockIdx.x] = block_part[0] + block_part[1] +
                           block_part[2] + block_part[3];
    }
}

// ---- final reduction: 4096 partials -> out[0], one block, no atomics ----
__global__ __launch_bounds__(1024) void reduce_partials(
    const float4* __restrict__ part4, float* __restrict__ out)
{
    __shared__ float ws[16];
    const float4 v = part4[threadIdx.x];         // 1024 x float4 = 4096 floats
    float s = v.x + v.y + v.z + v.w;
    #pragma unroll
    for (int off = 32; off; off >>= 1) s += __shfl_xor(s, off);
    const int wave = threadIdx.x >> 6;
    if ((threadIdx.x & 63) == 0) ws[wave] = s;
    __syncthreads();
    if (threadIdx.x == 0) {
        float t = 0.0f;
        #pragma unroll
        for (int i = 0; i < 16; ++i) t += ws[i];
        out[0] = t;
    }
}

// ---- fp32 fallback with the old atomic ending (only if d_ws is tiny) ----
__global__ __launch_bounds__(256) void infonce_f32_atomic(
    const float* __restrict__ emb,
    const int* __restrict__ targets,
    const int* __restrict__ contexts,
    const int* __restrict__ negatives,
    float* __restrict__ out)
{
    __shared__ float block_part[4];
    const int lane = threadIdx.x & 63;
    const int wib  = threadIdx.x >> 6;
    const int b    = blockIdx.x * 4 + wib;
    const int sub  = lane & 15;
    const int grp  = lane >> 4;

    const int* __restrict__ negb = negatives + b * NUM_NEG;
    int node[6];
    #pragma unroll
    for (int it = 0; it < 6; ++it) {
        const int r = it * 4 + grp;
        const int k = (r == 0) ? 0 : ((r <= NUM_NEG) ? (r - 1) : (NUM_NEG - 1));
        node[it] = (r == 0) ? contexts[b] : negb[k];
    }
    const int t_idx = targets[b];

    const float4* tp =
        reinterpret_cast<const float4*>(emb + (size_t)t_idx * DIM + sub * 8);
    const float4 t0 = tp[0];
    const float4 t1 = tp[1];

    float score[6];
    #pragma unroll
    for (int it = 0; it < 6; ++it) {
        const float4* vp = reinterpret_cast<const float4*>(
            emb + (size_t)node[it] * DIM + sub * 8);
        const float4 v0 = vp[0];
        const float4 v1 = vp[1];
        float p = t0.x * v0.x + t0.y * v0.y + t0.z * v0.z + t0.w * v0.w
                + t1.x * v1.x + t1.y * v1.y + t1.z * v1.z + t1.w * v1.w;
        p += __shfl_xor(p, 1);
        p += __shfl_xor(p, 2);
        p += __shfl_xor(p, 4);
        p += __shfl_xor(p, 8);
        const int r = it * 4 + grp;
        score[it] = (r < NROWS) ? p * INV_T : -INFINITY;
    }

    float m = score[0];
    #pragma unroll
    for (int i = 1; i < 6; ++i) m = fmaxf(m, score[i]);
    float s = 0.0f;
    #pragma unroll
    for (int i = 0; i < 6; ++i) s += expf(score[i] - m);

    #pragma unroll
    for (int mask = 16; mask <= 32; mask <<= 1) {
        const float mo = __shfl_xor(m, mask);
        const float so = __shfl_xor(s, mask);
        const float mn = fmaxf(m, mo);
        s = s * expf(m - mn) + so * expf(mo - mn);
        m = mn;
    }

    const float pos = __shfl(score[0], 0);
    const float loss = (m + logf(s) - pos) * (1.0f / BATCH);

    if (lane == 0) block_part[wib] = loss;
    __syncthreads();
    if (threadIdx.x == 0) {
        atomicAdd(out, block_part[0] + block_part[1] +
                       block_part[2] + block_part[3]);
    }
}

extern "C" void kernel_launch(void* const* d_in, const int* in_sizes, int n_in,
                              void* d_out, int out_size, void* d_ws, size_t ws_size,
                              hipStream_t stream) {
    const float* emb       = (const float*)d_in[0];
    const int*   targets   = (const int*)d_in[1];
    const int*   contexts  = (const int*)d_in[2];
    const int*   negatives = (const int*)d_in[3];
    float* out = (float*)d_out;

    const size_t tab_bytes  = (size_t)NUM_NODES * DIM * sizeof(_Float16); // 25.6 MB
    const size_t part_bytes = (size_t)NBLOCK * sizeof(float);             // 16 KB

    if (ws_size >= tab_bytes + part_bytes) {
        half8* tab  = (half8*)d_ws;
        float* part = (float*)((char*)d_ws + tab_bytes);  // 16B-aligned
        const int nchunk = NUM_NODES * DIM / 8;  // 1.6M
        convert_f16<<<dim3(2048), dim3(256), 0, stream>>>(emb, tab, nchunk);
        infonce_f16<<<dim3(NBLOCK), dim3(256), 0, stream>>>(
            tab, targets, contexts, negatives, part);
        reduce_partials<<<dim3(1), dim3(1024), 0, stream>>>(
            (const float4*)part, out);
    } else {
        hipMemsetAsync(out, 0, sizeof(float), stream);
        infonce_f32_atomic<<<dim3(BATCH / 4), dim3(256), 0, stream>>>(
            emb, targets, contexts, negatives, out);
    }
}

// Round 11
// 100.167 us; speedup vs baseline: 1.2901x; 1.0524x over previous
//
#include <hip/hip_runtime.h>
#include <math.h>

#define DIM 128
#define NUM_NEG 20
#define BATCH 16384
#define INV_T (1.0f / 0.07f)
#define NROWS 21
#define NUM_NODES 100000
#define NBLOCK (BATCH / 4)   // 4096 blocks, 4 waves each

// int8 dot of 4+4 packed bytes: acc += sum_k a8[k]*b8[k]
static __device__ __forceinline__ int dot4i8(int a, int b, int acc) {
#if __has_builtin(__builtin_amdgcn_sdot4)
    return __builtin_amdgcn_sdot4(a, b, acc, false);
#else
    #pragma unroll
    for (int k = 0; k < 4; ++k) {
        const int av = (a << (24 - 8 * k)) >> 24;
        const int bv = (b << (24 - 8 * k)) >> 24;
        acc += av * bv;
    }
    return acc;
#endif
}

// ---- fp32 -> int8 per-row-scaled table: qtab[row][128 B] + scales[row] ----
// Block = 16 groups x 16 lanes; one row per group. Lane handles 8 dims.
__global__ __launch_bounds__(256) void convert_q8(
    const float* __restrict__ in, uint2* __restrict__ qtab,
    float* __restrict__ scales)
{
    const int grp = threadIdx.x >> 4;
    const int l16 = threadIdx.x & 15;
    const int row = blockIdx.x * 16 + grp;
    if (row >= NUM_NODES) return;

    const float4* p =
        reinterpret_cast<const float4*>(in + (size_t)row * DIM + l16 * 8);
    const float4 a = p[0], c = p[1];
    float x[8] = {a.x, a.y, a.z, a.w, c.x, c.y, c.z, c.w};

    float am = 0.0f;
    #pragma unroll
    for (int j = 0; j < 8; ++j) am = fmaxf(am, fabsf(x[j]));
    am = fmaxf(am, __shfl_xor(am, 1));
    am = fmaxf(am, __shfl_xor(am, 2));
    am = fmaxf(am, __shfl_xor(am, 4));
    am = fmaxf(am, __shfl_xor(am, 8));
    am = fmaxf(am, 1e-20f);

    const float inv = 127.0f / am;
    int q[8];
    #pragma unroll
    for (int j = 0; j < 8; ++j) {
        int v = (int)rintf(x[j] * inv);
        q[j] = min(127, max(-127, v));
    }
    uint32_t lo = (q[0] & 0xff) | ((q[1] & 0xff) << 8) |
                  ((q[2] & 0xff) << 16) | ((uint32_t)(q[3] & 0xff) << 24);
    uint32_t hi = (q[4] & 0xff) | ((q[5] & 0xff) << 8) |
                  ((q[6] & 0xff) << 16) | ((uint32_t)(q[7] & 0xff) << 24);
    qtab[(size_t)row * 16 + l16] = make_uint2(lo, hi);
    if (l16 == 0) scales[row] = am / 127.0f;
}

// ---- int8 gather: one wave per batch element, 4 groups x 16 lanes.
// 128 B int8 row = 2 fully-used 64B lines (half of fp16's 4). Exact int
// partial dot per lane (sdot4), int lane-reduce, scales applied once. ----
__global__ __launch_bounds__(256) void infonce_q8(
    const uint2* __restrict__ qtab,
    const float* __restrict__ scales,
    const int* __restrict__ targets,
    const int* __restrict__ contexts,
    const int* __restrict__ negatives,
    float* __restrict__ part)        // [NBLOCK] partials
{
    __shared__ float block_part[4];
    const int lane = threadIdx.x & 63;
    const int wib  = threadIdx.x >> 6;
    const int b    = blockIdx.x * 4 + wib;
    const int sub  = lane & 15;          // 8-byte chunk within the row
    const int grp  = lane >> 4;          // row-group 0..3

    // phase 1: all index loads
    const int* __restrict__ negb = negatives + b * NUM_NEG;
    int node[6];
    #pragma unroll
    for (int it = 0; it < 6; ++it) {
        const int r = it * 4 + grp;      // 0..23 (21..23 invalid -> alias row 20)
        const int k = (r == 0) ? 0 : ((r <= NUM_NEG) ? (r - 1) : (NUM_NEG - 1));
        node[it] = (r == 0) ? contexts[b] : negb[k];
    }
    const int t_idx = targets[b];

    // phase 2: all row gathers back-to-back (max MLP)
    const uint2 tq = qtab[(size_t)t_idx * 16 + sub];
    const float st = scales[t_idx];
    uint2 vq[6];
    float sv[6];
    #pragma unroll
    for (int it = 0; it < 6; ++it) {
        vq[it] = qtab[(size_t)node[it] * 16 + sub];
        sv[it] = scales[node[it]];
    }

    // phase 3: exact int8 dot + int 16-lane reduce per slot
    float score[6];
    #pragma unroll
    for (int it = 0; it < 6; ++it) {
        int d = dot4i8(tq.x, vq[it].x, 0);
        d = dot4i8(tq.y, vq[it].y, d);
        d += __shfl_xor(d, 1);
        d += __shfl_xor(d, 2);
        d += __shfl_xor(d, 4);
        d += __shfl_xor(d, 8);
        const int r = it * 4 + grp;
        score[it] = (r < NROWS) ? (float)d * st * sv[it] * INV_T : -INFINITY;
    }

    // phase 4: logsumexp (local 6, then merge across 4 groups)
    float m = score[0];
    #pragma unroll
    for (int i = 1; i < 6; ++i) m = fmaxf(m, score[i]);
    float s = 0.0f;
    #pragma unroll
    for (int i = 0; i < 6; ++i) s += expf(score[i] - m);

    #pragma unroll
    for (int mask = 16; mask <= 32; mask <<= 1) {
        const float mo = __shfl_xor(m, mask);
        const float so = __shfl_xor(s, mask);
        const float mn = fmaxf(m, mo);
        s = s * expf(m - mn) + so * expf(mo - mn);
        m = mn;
    }

    const float pos = __shfl(score[0], 0);
    const float loss = (m + logf(s) - pos) * (1.0f / BATCH);

    if (lane == 0) block_part[wib] = loss;
    __syncthreads();
    if (threadIdx.x == 0) {
        part[blockIdx.x] = block_part[0] + block_part[1] +
                           block_part[2] + block_part[3];
    }
}

// ---- final reduction: 4096 partials -> out[0], one block, no atomics ----
__global__ __launch_bounds__(1024) void reduce_partials(
    const float4* __restrict__ part4, float* __restrict__ out)
{
    __shared__ float ws[16];
    const float4 v = part4[threadIdx.x];         // 1024 x float4 = 4096 floats
    float s = v.x + v.y + v.z + v.w;
    #pragma unroll
    for (int off = 32; off; off >>= 1) s += __shfl_xor(s, off);
    const int wave = threadIdx.x >> 6;
    if ((threadIdx.x & 63) == 0) ws[wave] = s;
    __syncthreads();
    if (threadIdx.x == 0) {
        float t = 0.0f;
        #pragma unroll
        for (int i = 0; i < 16; ++i) t += ws[i];
        out[0] = t;
    }
}

// ---- fp32 fallback with atomic ending (only if d_ws is tiny) ----
__global__ __launch_bounds__(256) void infonce_f32_atomic(
    const float* __restrict__ emb,
    const int* __restrict__ targets,
    const int* __restrict__ contexts,
    const int* __restrict__ negatives,
    float* __restrict__ out)
{
    __shared__ float block_part[4];
    const int lane = threadIdx.x & 63;
    const int wib  = threadIdx.x >> 6;
    const int b    = blockIdx.x * 4 + wib;
    const int sub  = lane & 15;
    const int grp  = lane >> 4;

    const int* __restrict__ negb = negatives + b * NUM_NEG;
    int node[6];
    #pragma unroll
    for (int it = 0; it < 6; ++it) {
        const int r = it * 4 + grp;
        const int k = (r == 0) ? 0 : ((r <= NUM_NEG) ? (r - 1) : (NUM_NEG - 1));
        node[it] = (r == 0) ? contexts[b] : negb[k];
    }
    const int t_idx = targets[b];

    const float4* tp =
        reinterpret_cast<const float4*>(emb + (size_t)t_idx * DIM + sub * 8);
    const float4 t0 = tp[0];
    const float4 t1 = tp[1];

    float score[6];
    #pragma unroll
    for (int it = 0; it < 6; ++it) {
        const float4* vp = reinterpret_cast<const float4*>(
            emb + (size_t)node[it] * DIM + sub * 8);
        const float4 v0 = vp[0];
        const float4 v1 = vp[1];
        float p = t0.x * v0.x + t0.y * v0.y + t0.z * v0.z + t0.w * v0.w
                + t1.x * v1.x + t1.y * v1.y + t1.z * v1.z + t1.w * v1.w;
        p += __shfl_xor(p, 1);
        p += __shfl_xor(p, 2);
        p += __shfl_xor(p, 4);
        p += __shfl_xor(p, 8);
        const int r = it * 4 + grp;
        score[it] = (r < NROWS) ? p * INV_T : -INFINITY;
    }

    float m = score[0];
    #pragma unroll
    for (int i = 1; i < 6; ++i) m = fmaxf(m, score[i]);
    float s = 0.0f;
    #pragma unroll
    for (int i = 0; i < 6; ++i) s += expf(score[i] - m);

    #pragma unroll
    for (int mask = 16; mask <= 32; mask <<= 1) {
        const float mo = __shfl_xor(m, mask);
        const float so = __shfl_xor(s, mask);
        const float mn = fmaxf(m, mo);
        s = s * expf(m - mn) + so * expf(mo - mn);
        m = mn;
    }

    const float pos = __shfl(score[0], 0);
    const float loss = (m + logf(s) - pos) * (1.0f / BATCH);

    if (lane == 0) block_part[wib] = loss;
    __syncthreads();
    if (threadIdx.x == 0) {
        atomicAdd(out, block_part[0] + block_part[1] +
                       block_part[2] + block_part[3]);
    }
}

extern "C" void kernel_launch(void* const* d_in, const int* in_sizes, int n_in,
                              void* d_out, int out_size, void* d_ws, size_t ws_size,
                              hipStream_t stream) {
    const float* emb       = (const float*)d_in[0];
    const int*   targets   = (const int*)d_in[1];
    const int*   contexts  = (const int*)d_in[2];
    const int*   negatives = (const int*)d_in[3];
    float* out = (float*)d_out;

    const size_t qtab_bytes  = (size_t)NUM_NODES * DIM;          // 12.8 MB
    const size_t scale_bytes = (size_t)NUM_NODES * sizeof(float); // 400 KB
    const size_t part_bytes  = (size_t)NBLOCK * sizeof(float);    // 16 KB

    if (ws_size >= qtab_bytes + scale_bytes + part_bytes) {
        uint2* qtab   = (uint2*)d_ws;
        float* scales = (float*)((char*)d_ws + qtab_bytes);
        float* part   = (float*)((char*)d_ws + qtab_bytes + scale_bytes);

        convert_q8<<<dim3((NUM_NODES + 15) / 16), dim3(256), 0, stream>>>(
            emb, qtab, scales);
        infonce_q8<<<dim3(NBLOCK), dim3(256), 0, stream>>>(
            qtab, scales, targets, contexts, negatives, part);
        reduce_partials<<<dim3(1), dim3(1024), 0, stream>>>(
            (const float4*)part, out);
    } else {
        hipMemsetAsync(out, 0, sizeof(float), stream);
        infonce_f32_atomic<<<dim3(BATCH / 4), dim3(256), 0, stream>>>(
            emb, targets, contexts, negatives, out);
    }
}

// Round 13
// 99.644 us; speedup vs baseline: 1.2968x; 1.0053x over previous
//
#include <hip/hip_runtime.h>
#include <math.h>

#define DIM 128
#define NUM_NEG 20
#define BATCH 16384
#define INV_T (1.0f / 0.07f)
#define NROWS 21
#define NUM_NODES 100000
#define NBLOCK (BATCH / 4)   // 4096 blocks, 4 waves each

// int8 dot of 4+4 packed bytes: acc += sum_k a8[k]*b8[k]
static __device__ __forceinline__ int dot4i8(int a, int b, int acc) {
#if __has_builtin(__builtin_amdgcn_sdot4)
    return __builtin_amdgcn_sdot4(a, b, acc, false);
#else
    #pragma unroll
    for (int k = 0; k < 4; ++k) {
        const int av = (a << (24 - 8 * k)) >> 24;
        const int bv = (b << (24 - 8 * k)) >> 24;
        acc += av * bv;
    }
    return acc;
#endif
}

// ---- fp32 -> int8 per-row-scaled table: qtab[row][128 B] + scales[row] ----
// Block = 16 groups x 16 lanes; one row per group. Lane handles 8 dims.
__global__ __launch_bounds__(256) void convert_q8(
    const float* __restrict__ in, uint2* __restrict__ qtab,
    float* __restrict__ scales)
{
    const int grp = threadIdx.x >> 4;
    const int l16 = threadIdx.x & 15;
    const int row = blockIdx.x * 16 + grp;
    if (row >= NUM_NODES) return;

    const float4* p =
        reinterpret_cast<const float4*>(in + (size_t)row * DIM + l16 * 8);
    const float4 a = p[0], c = p[1];
    float x[8] = {a.x, a.y, a.z, a.w, c.x, c.y, c.z, c.w};

    float am = 0.0f;
    #pragma unroll
    for (int j = 0; j < 8; ++j) am = fmaxf(am, fabsf(x[j]));
    am = fmaxf(am, __shfl_xor(am, 1));
    am = fmaxf(am, __shfl_xor(am, 2));
    am = fmaxf(am, __shfl_xor(am, 4));
    am = fmaxf(am, __shfl_xor(am, 8));
    am = fmaxf(am, 1e-20f);

    const float inv = 127.0f / am;
    int q[8];
    #pragma unroll
    for (int j = 0; j < 8; ++j) {
        int v = (int)rintf(x[j] * inv);
        q[j] = min(127, max(-127, v));
    }
    uint32_t lo = (q[0] & 0xff) | ((q[1] & 0xff) << 8) |
                  ((q[2] & 0xff) << 16) | ((uint32_t)(q[3] & 0xff) << 24);
    uint32_t hi = (q[4] & 0xff) | ((q[5] & 0xff) << 8) |
                  ((q[6] & 0xff) << 16) | ((uint32_t)(q[7] & 0xff) << 24);
    qtab[(size_t)row * 16 + l16] = make_uint2(lo, hi);
    if (l16 == 0) scales[row] = am / 127.0f;
}

// ---- int8 gather: one wave per batch element, 4 groups x 16 lanes.
// 128 B int8 row = 2 fully-used 64B lines (half of fp16's 4). Exact int
// partial dot per lane (sdot4), int lane-reduce, scales applied once. ----
__global__ __launch_bounds__(256) void infonce_q8(
    const uint2* __restrict__ qtab,
    const float* __restrict__ scales,
    const int* __restrict__ targets,
    const int* __restrict__ contexts,
    const int* __restrict__ negatives,
    float* __restrict__ part)        // [NBLOCK] partials
{
    __shared__ float block_part[4];
    const int lane = threadIdx.x & 63;
    const int wib  = threadIdx.x >> 6;
    const int b    = blockIdx.x * 4 + wib;
    const int sub  = lane & 15;          // 8-byte chunk within the row
    const int grp  = lane >> 4;          // row-group 0..3

    // phase 1: all index loads
    const int* __restrict__ negb = negatives + b * NUM_NEG;
    int node[6];
    #pragma unroll
    for (int it = 0; it < 6; ++it) {
        const int r = it * 4 + grp;      // 0..23 (21..23 invalid -> alias row 20)
        const int k = (r == 0) ? 0 : ((r <= NUM_NEG) ? (r - 1) : (NUM_NEG - 1));
        node[it] = (r == 0) ? contexts[b] : negb[k];
    }
    const int t_idx = targets[b];

    // phase 2: all row gathers back-to-back (max MLP)
    const uint2 tq = qtab[(size_t)t_idx * 16 + sub];
    const float st = scales[t_idx];
    uint2 vq[6];
    float sv[6];
    #pragma unroll
    for (int it = 0; it < 6; ++it) {
        vq[it] = qtab[(size_t)node[it] * 16 + sub];
        sv[it] = scales[node[it]];
    }

    // phase 3: exact int8 dot + int 16-lane reduce per slot
    float score[6];
    #pragma unroll
    for (int it = 0; it < 6; ++it) {
        int d = dot4i8(tq.x, vq[it].x, 0);
        d = dot4i8(tq.y, vq[it].y, d);
        d += __shfl_xor(d, 1);
        d += __shfl_xor(d, 2);
        d += __shfl_xor(d, 4);
        d += __shfl_xor(d, 8);
        const int r = it * 4 + grp;
        score[it] = (r < NROWS) ? (float)d * st * sv[it] * INV_T : -INFINITY;
    }

    // phase 4: logsumexp (local 6, then merge across 4 groups)
    float m = score[0];
    #pragma unroll
    for (int i = 1; i < 6; ++i) m = fmaxf(m, score[i]);
    float s = 0.0f;
    #pragma unroll
    for (int i = 0; i < 6; ++i) s += expf(score[i] - m);

    #pragma unroll
    for (int mask = 16; mask <= 32; mask <<= 1) {
        const float mo = __shfl_xor(m, mask);
        const float so = __shfl_xor(s, mask);
        const float mn = fmaxf(m, mo);
        s = s * expf(m - mn) + so * expf(mo - mn);
        m = mn;
    }

    const float pos = __shfl(score[0], 0);
    const float loss = (m + logf(s) - pos) * (1.0f / BATCH);

    if (lane == 0) block_part[wib] = loss;
    __syncthreads();
    if (threadIdx.x == 0) {
        part[blockIdx.x] = block_part[0] + block_part[1] +
                           block_part[2] + block_part[3];
    }
}

// ---- final reduction: 4096 partials -> out[0], one block, no atomics ----
__global__ __launch_bounds__(1024) void reduce_partials(
    const float4* __restrict__ part4, float* __restrict__ out)
{
    __shared__ float ws[16];
    const float4 v = part4[threadIdx.x];         // 1024 x float4 = 4096 floats
    float s = v.x + v.y + v.z + v.w;
    #pragma unroll
    for (int off = 32; off; off >>= 1) s += __shfl_xor(s, off);
    const int wave = threadIdx.x >> 6;
    if ((threadIdx.x & 63) == 0) ws[wave] = s;
    __syncthreads();
    if (threadIdx.x == 0) {
        float t = 0.0f;
        #pragma unroll
        for (int i = 0; i < 16; ++i) t += ws[i];
        out[0] = t;
    }
}

// ---- fp32 fallback with atomic ending (only if d_ws is tiny) ----
__global__ __launch_bounds__(256) void infonce_f32_atomic(
    const float* __restrict__ emb,
    const int* __restrict__ targets,
    const int* __restrict__ contexts,
    const int* __restrict__ negatives,
    float* __restrict__ out)
{
    __shared__ float block_part[4];
    const int lane = threadIdx.x & 63;
    const int wib  = threadIdx.x >> 6;
    const int b    = blockIdx.x * 4 + wib;
    const int sub  = lane & 15;
    const int grp  = lane >> 4;

    const int* __restrict__ negb = negatives + b * NUM_NEG;
    int node[6];
    #pragma unroll
    for (int it = 0; it < 6; ++it) {
        const int r = it * 4 + grp;
        const int k = (r == 0) ? 0 : ((r <= NUM_NEG) ? (r - 1) : (NUM_NEG - 1));
        node[it] = (r == 0) ? contexts[b] : negb[k];
    }
    const int t_idx = targets[b];

    const float4* tp =
        reinterpret_cast<const float4*>(emb + (size_t)t_idx * DIM + sub * 8);
    const float4 t0 = tp[0];
    const float4 t1 = tp[1];

    float score[6];
    #pragma unroll
    for (int it = 0; it < 6; ++it) {
        const float4* vp = reinterpret_cast<const float4*>(
            emb + (size_t)node[it] * DIM + sub * 8);
        const float4 v0 = vp[0];
        const float4 v1 = vp[1];
        float p = t0.x * v0.x + t0.y * v0.y + t0.z * v0.z + t0.w * v0.w
                + t1.x * v1.x + t1.y * v1.y + t1.z * v1.z + t1.w * v1.w;
        p += __shfl_xor(p, 1);
        p += __shfl_xor(p, 2);
        p += __shfl_xor(p, 4);
        p += __shfl_xor(p, 8);
        const int r = it * 4 + grp;
        score[it] = (r < NROWS) ? p * INV_T : -INFINITY;
    }

    float m = score[0];
    #pragma unroll
    for (int i = 1; i < 6; ++i) m = fmaxf(m, score[i]);
    float s = 0.0f;
    #pragma unroll
    for (int i = 0; i < 6; ++i) s += expf(score[i] - m);

    #pragma unroll
    for (int mask = 16; mask <= 32; mask <<= 1) {
        const float mo = __shfl_xor(m, mask);
        const float so = __shfl_xor(s, mask);
        const float mn = fmaxf(m, mo);
        s = s * expf(m - mn) + so * expf(mo - mn);
        m = mn;
    }

    const float pos = __shfl(score[0], 0);
    const float loss = (m + logf(s) - pos) * (1.0f / BATCH);

    if (lane == 0) block_part[wib] = loss;
    __syncthreads();
    if (threadIdx.x == 0) {
        atomicAdd(out, block_part[0] + block_part[1] +
                       block_part[2] + block_part[3]);
    }
}

extern "C" void kernel_launch(void* const* d_in, const int* in_sizes, int n_in,
                              void* d_out, int out_size, void* d_ws, size_t ws_size,
                              hipStream_t stream) {
    const float* emb       = (const float*)d_in[0];
    const int*   targets   = (const int*)d_in[1];
    const int*   contexts  = (const int*)d_in[2];
    const int*   negatives = (const int*)d_in[3];
    float* out = (float*)d_out;

    const size_t qtab_bytes  = (size_t)NUM_NODES * DIM;          // 12.8 MB
    const size_t scale_bytes = (size_t)NUM_NODES * sizeof(float); // 400 KB
    const size_t part_bytes  = (size_t)NBLOCK * sizeof(float);    // 16 KB

    if (ws_size >= qtab_bytes + scale_bytes + part_bytes) {
        uint2* qtab   = (uint2*)d_ws;
        float* scales = (float*)((char*)d_ws + qtab_bytes);
        float* part   = (float*)((char*)d_ws + qtab_bytes + scale_bytes);

        convert_q8<<<dim3((NUM_NODES + 15) / 16), dim3(256), 0, stream>>>(
            emb, qtab, scales);
        infonce_q8<<<dim3(NBLOCK), dim3(256), 0, stream>>>(
            qtab, scales, targets, contexts, negatives, part);
        reduce_partials<<<dim3(1), dim3(1024), 0, stream>>>(
            (const float4*)part, out);
    } else {
        hipMemsetAsync(out, 0, sizeof(float), stream);
        infonce_f32_atomic<<<dim3(BATCH / 4), dim3(256), 0, stream>>>(
            emb, targets, contexts, negatives, out);
    }
}